// Round 1
// baseline (155.324 us; speedup 1.0000x reference)
//
#include <hip/hip_runtime.h>
#include <hip/hip_bf16.h>

// Pairwise Euclidean min-distance: out[i] = 10 * min_j ||x_i - y_j||
// x: 8192x96 fp32, y: 65536x96 fp32.
// Strategy: sq = x2[i] + (y2[j] - 2*x.y) ; bf16 MFMA computes (y2 - 2*x.y)
// directly by pre-scaling train by -2 (exact in bf16) and preloading y2 as
// the MFMA C operand. Row-min folds inside lanes (train = M operand).

typedef __attribute__((ext_vector_type(8))) short bf16x8;
typedef __attribute__((ext_vector_type(4))) float f32x4;

#define NQ 8192
#define NT 65536
#define KD 96
#define QB 256           // queries per workgroup (4 waves x 64)
#define TSPLIT 32        // train chunks
#define TCHUNK (NT / TSPLIT)   // 2048 train rows per WG
#define TTILE 128        // train rows staged in LDS per iteration
#define LDS_STRIDE 104   // ushort elems per row: 96 data + 8 pad (2-way banks)

static __device__ __forceinline__ ushort f2bf(float f) {
  // round-to-nearest-even bf16 (inputs are finite)
  unsigned u = __float_as_uint(f);
  unsigned r = (u + 0x7fffu + ((u >> 16) & 1u)) >> 16;
  return (ushort)r;
}

__global__ __launch_bounds__(256) void prep_kernel(
    const float* __restrict__ qf, const float* __restrict__ tf,
    ushort* __restrict__ qbf, ushort* __restrict__ tbf,
    float* __restrict__ x2, float* __restrict__ y2,
    float* __restrict__ outp)
{
  const int w = threadIdx.x >> 6, lane = threadIdx.x & 63;
  const int b = blockIdx.x;
  const float* src; ushort* dst; float* nrm; int p; bool isq;
  if (b < NQ / 4) {
    p = b * 4 + w; src = qf + (size_t)p * KD; dst = qbf + (size_t)p * KD;
    nrm = x2; isq = true;
  } else {
    p = (b - NQ / 4) * 4 + w; src = tf + (size_t)p * KD; dst = tbf + (size_t)p * KD;
    nrm = y2; isq = false;
  }
  float a = src[lane];
  float c = (lane < 32) ? src[64 + lane] : 0.0f;
  // train stored pre-scaled by -2 (power of two => exact in bf16)
  float sa = isq ? a : -2.0f * a;
  float sc = isq ? c : -2.0f * c;
  dst[lane] = f2bf(sa);
  if (lane < 32) dst[64 + lane] = f2bf(sc);
  float s = fmaf(a, a, c * c);
  #pragma unroll
  for (int off = 1; off < 64; off <<= 1) s += __shfl_xor(s, off, 64);
  if (lane == 0) {
    nrm[p] = s;
    if (isq) outp[p] = __uint_as_float(0x7f800000u);  // +inf
  }
}

__global__ __launch_bounds__(256, 4) void min_dist_kernel(
    const ushort* __restrict__ qbf, const ushort* __restrict__ tbf,
    const float* __restrict__ x2, const float* __restrict__ y2,
    float* __restrict__ outp)
{
  __shared__ ushort ldsA[TTILE * LDS_STRIDE];
  __shared__ float ldsY[TTILE];

  const int tid  = threadIdx.x;
  const int w    = tid >> 6;
  const int lane = tid & 63;
  const int quad = lane >> 4;
  const int n    = lane & 15;
  // tsplit = blockIdx % 32 -> all 32 WGs of one train chunk share an XCD
  const int tsplit = blockIdx.x & (TSPLIT - 1);
  const int qblock = blockIdx.x / TSPLIT;
  const int qbase  = qblock * QB + w * 64;

  // Query (B-operand) fragments: 4 col-tiles x 3 k-blocks, held all kernel.
  // B frag layout: lane holds B[k=quad*8+j][n=lane&15] = q[n][quad*8+j].
  bf16x8 bq[4][3];
  #pragma unroll
  for (int ct = 0; ct < 4; ++ct) {
    const ushort* qp = qbf + (size_t)(qbase + ct * 16 + n) * KD + quad * 8;
    #pragma unroll
    for (int kb = 0; kb < 3; ++kb)
      bq[ct][kb] = *(const bf16x8*)(qp + kb * 32);
  }

  const float INF = __uint_as_float(0x7f800000u);
  float m0 = INF, m1 = INF, m2 = INF, m3 = INF;

  const int trow0 = tsplit * TCHUNK;
  #pragma unroll 1
  for (int tile = 0; tile < TCHUNK / TTILE; ++tile) {
    const int tb = trow0 + tile * TTILE;
    __syncthreads();
    // Stage 128 rows x 96 bf16 (global contiguous: chunk d -> byte d*16)
    const ushort* gsrc = tbf + (size_t)tb * KD;
    #pragma unroll
    for (int it = 0; it < 6; ++it) {
      int d = it * 256 + tid;          // 16B chunk id, 0..1535
      int row = d / 12;
      int c = d - row * 12;
      uint4 v = *(const uint4*)(gsrc + d * 8);
      *(uint4*)&ldsA[row * LDS_STRIDE + c * 8] = v;
    }
    if (tid < 32)
      *(float4*)&ldsY[tid * 4] = *(const float4*)(y2 + tb + tid * 4);
    __syncthreads();

    #pragma unroll
    for (int tt = 0; tt < 8; ++tt) {
      // A frag: lane holds A[m=lane&15][k=quad*8+j] = train[tt*16+n][...]
      const ushort* ap = &ldsA[(tt * 16 + n) * LDS_STRIDE + quad * 8];
      bf16x8 a0 = *(const bf16x8*)(ap);
      bf16x8 a1 = *(const bf16x8*)(ap + 32);
      bf16x8 a2 = *(const bf16x8*)(ap + 64);
      // C preload = y2 rows (C/D row = quad*4 + reg)
      f32x4 y2v = *(const f32x4*)&ldsY[tt * 16 + quad * 4];
      #pragma unroll
      for (int ct = 0; ct < 4; ++ct) {
        f32x4 acc = __builtin_amdgcn_mfma_f32_16x16x32_bf16(a0, bq[ct][0], y2v, 0, 0, 0);
        acc = __builtin_amdgcn_mfma_f32_16x16x32_bf16(a1, bq[ct][1], acc, 0, 0, 0);
        acc = __builtin_amdgcn_mfma_f32_16x16x32_bf16(a2, bq[ct][2], acc, 0, 0, 0);
        // acc[r] = y2[row] - 2*dot ; min over train rows folds in-lane
        float t0 = fminf(acc[0], acc[1]);
        float t1 = fminf(acc[2], acc[3]);
        float t = fminf(t0, t1);
        if (ct == 0) m0 = fminf(m0, t);
        else if (ct == 1) m1 = fminf(m1, t);
        else if (ct == 2) m2 = fminf(m2, t);
        else m3 = fminf(m3, t);
      }
    }
  }

  // Combine across quads: lanes with equal n hold the same query columns.
  float m[4] = {m0, m1, m2, m3};
  #pragma unroll
  for (int ct = 0; ct < 4; ++ct) {
    m[ct] = fminf(m[ct], __shfl_xor(m[ct], 16, 64));
    m[ct] = fminf(m[ct], __shfl_xor(m[ct], 32, 64));
  }
  if (quad == 0) {
    #pragma unroll
    for (int ct = 0; ct < 4; ++ct) {
      int q = qbase + ct * 16 + n;
      float sq = fmaxf(x2[q] + m[ct], 0.0f);
      float val = sqrtf(sq) * 10.0f;
      atomicMin((unsigned int*)&outp[q], __float_as_uint(val));
    }
  }
}

extern "C" void kernel_launch(void* const* d_in, const int* in_sizes, int n_in,
                              void* d_out, int out_size, void* d_ws, size_t ws_size,
                              hipStream_t stream) {
  const float* qf = (const float*)d_in[0];   // mutation_dist 8192x96
  const float* tf = (const float*)d_in[1];   // train_data   65536x96
  float* outp = (float*)d_out;               // 8192 fp32

  // workspace layout (~14.5 MB)
  ushort* qbf = (ushort*)d_ws;               // 8192*96 bf16
  ushort* tbf = qbf + (size_t)NQ * KD;       // 65536*96 bf16 (pre-scaled -2)
  float* x2 = (float*)(tbf + (size_t)NT * KD);
  float* y2 = x2 + NQ;

  prep_kernel<<<(NQ + NT) / 4, 256, 0, stream>>>(qf, tf, qbf, tbf, x2, y2, outp);
  min_dist_kernel<<<(NQ / QB) * TSPLIT, 256, 0, stream>>>(qbf, tbf, x2, y2, outp);
}